// Round 1
// baseline (250.429 us; speedup 1.0000x reference)
//
#include <hip/hip_runtime.h>

#define T_LEN 512
#define NHID 16
#define NEMB 10

// 16 lanes per batch element: lane j owns hidden unit j and gate rows
// {j, j+16, j+32, j+48}. 4 batch elements per wave, 4 waves per block
// -> 16 batch/block, grid = 256 blocks (4096 batches), 1024 waves total.
__global__ __launch_bounds__(256) void lstm_kernel(
    const int*   __restrict__ x,    // [B, 512]
    const float* __restrict__ emb,  // [50001, 10]
    const float* __restrict__ Wih,  // [64, 10]
    const float* __restrict__ Whh,  // [64, 16]
    const float* __restrict__ bih,  // [64]
    const float* __restrict__ bhh,  // [64]
    const float* __restrict__ Wfc,  // [16]
    const float* __restrict__ bfc,  // [1]
    float*       __restrict__ out)  // [B]
{
    __shared__ int idx_lds[T_LEN][16];   // [t][local_batch] 32 KB

    const int tid  = threadIdx.x;
    const int lane = tid & 63;
    const int j    = lane & 15;          // hidden unit owned by this lane
    const int lb   = tid >> 4;           // local batch 0..15
    const int batch = blockIdx.x * 16 + lb;

    // stage indices: coalesced in t, layout [t][lb] so the 4 groups of a wave
    // read 4 distinct banks (broadcast within each 16-lane group)
    for (int i = tid; i < 16 * T_LEN; i += 256) {
        int b = i >> 9;
        int t = i & (T_LEN - 1);
        idx_lds[t][b] = x[(blockIdx.x * 16 + b) * T_LEN + t];
    }

    // per-lane weights in registers: 4 gate rows (i,f,g,o order: q*16 + j)
    float wih[4][NEMB], whh[4][NHID], bias[4];
    #pragma unroll
    for (int q = 0; q < 4; ++q) {
        const int r = j + 16 * q;
        #pragma unroll
        for (int e = 0; e < NEMB; ++e) wih[q][e] = Wih[r * NEMB + e];
        #pragma unroll
        for (int k = 0; k < NHID; ++k) whh[q][k] = Whh[r * NHID + k];
        bias[q] = bih[r] + bhh[r];
    }

    __syncthreads();

    float h[NHID];
    #pragma unroll
    for (int k = 0; k < NHID; ++k) h[k] = 0.f;
    float c = 0.f;

    const float NL2E  = -1.44269504088896f;   // -log2(e)
    const float NL2E2 = -2.88539008177793f;   // -2*log2(e)
    const int   bse   = lane & 48;            // group base lane for shuffles

    // prefetch emb row for t=0 (emb rows are 40B = 8B-aligned -> float2 loads)
    float2 xa, xb, xc, xd, xe2;
    {
        const int idx0 = idx_lds[0][lb];
        const float2* er = (const float2*)(emb + idx0 * NEMB);
        xa = er[0]; xb = er[1]; xc = er[2]; xd = er[3]; xe2 = er[4];
    }

    #pragma unroll 1
    for (int t = 0; t < T_LEN; ++t) {
        const float xv[NEMB] = {xa.x, xa.y, xb.x, xb.y, xc.x, xc.y,
                                xd.x, xd.y, xe2.x, xe2.y};
        // issue next timestep's embedding load (hides L2 latency under compute)
        if (t + 1 < T_LEN) {
            const int idxn = idx_lds[t + 1][lb];
            const float2* er = (const float2*)(emb + idxn * NEMB);
            xa = er[0]; xb = er[1]; xc = er[2]; xd = er[3]; xe2 = er[4];
        }

        // gate pre-activations: v[q] = bias + xe.Wih_row + h.Whh_row
        float v[4];
        #pragma unroll
        for (int q = 0; q < 4; ++q) {
            float a = bias[q];
            #pragma unroll
            for (int e = 0; e < NEMB; ++e) a += xv[e] * wih[q][e];
            #pragma unroll
            for (int k = 0; k < NHID; ++k) a += h[k] * whh[q][k];
            v[q] = a;
        }

        // nonlinearities: sigmoid(x) = rcp(1 + exp2(-x*log2e)); tanh = 2*sig(2x)-1
        const float ig = __builtin_amdgcn_rcpf(1.f + __builtin_amdgcn_exp2f(v[0] * NL2E));
        const float fg = __builtin_amdgcn_rcpf(1.f + __builtin_amdgcn_exp2f(v[1] * NL2E));
        const float gg = 2.f * __builtin_amdgcn_rcpf(1.f + __builtin_amdgcn_exp2f(v[2] * NL2E2)) - 1.f;
        const float og = __builtin_amdgcn_rcpf(1.f + __builtin_amdgcn_exp2f(v[3] * NL2E));

        c = fg * c + ig * gg;
        const float tc = 2.f * __builtin_amdgcn_rcpf(1.f + __builtin_amdgcn_exp2f(c * NL2E2)) - 1.f;
        const float hv = og * tc;

        // broadcast h across the 16-lane group (addresses loop-invariant)
        #pragma unroll
        for (int k = 0; k < NHID; ++k)
            h[k] = __shfl(hv, bse + k, 64);
    }

    if (j == 0) {
        float logit = bfc[0];
        #pragma unroll
        for (int k = 0; k < NHID; ++k) logit += h[k] * Wfc[k];
        out[batch] = __builtin_amdgcn_rcpf(1.f + __builtin_amdgcn_exp2f(logit * NL2E));
    }
}

extern "C" void kernel_launch(void* const* d_in, const int* in_sizes, int n_in,
                              void* d_out, int out_size, void* d_ws, size_t ws_size,
                              hipStream_t stream) {
    const int*   x   = (const int*)  d_in[0];
    const float* emb = (const float*)d_in[1];
    const float* Wih = (const float*)d_in[2];
    const float* Whh = (const float*)d_in[3];
    const float* bih = (const float*)d_in[4];
    const float* bhh = (const float*)d_in[5];
    const float* Wfc = (const float*)d_in[6];
    const float* bfc = (const float*)d_in[7];
    float* outp = (float*)d_out;

    const int B = in_sizes[0] / T_LEN;   // 4096
    lstm_kernel<<<B / 16, 256, 0, stream>>>(x, emb, Wih, Whh, bih, bhh, Wfc, bfc, outp);
}

// Round 2
// 173.778 us; speedup vs baseline: 1.4411x; 1.4411x over previous
//
#include <hip/hip_runtime.h>

#define T_LEN 512
#define NHID 16
#define NEMB 10
#define VOCAB1 50001

typedef float v2f __attribute__((ext_vector_type(2)));

// ---------------------------------------------------------------------------
// Kernel 1: precompute xproj table. tbl[v][j][q] = (bih+bhh)[q*16+j]
//           + sum_e emb[v][e] * Wih[q*16+j][e].   Layout: [VOCAB1][16][4] f32.
// Lane j of a 16-thread slice reads float4 tbl[v*16+j] -> 256B coalesced/row.
// ---------------------------------------------------------------------------
__global__ __launch_bounds__(256) void build_table(
    const float* __restrict__ emb, const float* __restrict__ Wih,
    const float* __restrict__ bih, const float* __restrict__ bhh,
    float* __restrict__ tbl)
{
    const int tid = blockIdx.x * 256 + threadIdx.x;
    if (tid >= VOCAB1 * 16) return;
    const int v = tid >> 4, j = tid & 15;
    float e[NEMB];
    #pragma unroll
    for (int i = 0; i < NEMB; ++i) e[i] = emb[v * NEMB + i];
    float o[4];
    #pragma unroll
    for (int q = 0; q < 4; ++q) {
        const int r = q * 16 + j;
        float a = bih[r] + bhh[r];
        #pragma unroll
        for (int i = 0; i < NEMB; ++i) a += e[i] * Wih[r * NEMB + i];
        o[q] = a;
    }
    ((float4*)tbl)[tid] = make_float4(o[0], o[1], o[2], o[3]);
}

// ---------------------------------------------------------------------------
// Kernel 2 (table path): 16 lanes/batch, lane j owns hidden unit j and all 4
// gate rows {j,j+16,j+32,j+48}. 4 batch/wave, 4 waves/block, 256 blocks.
// h-exchange: 1 ds_write + 4 ds_read_b128 from wave-private LDS (not 16
// bpermutes). Loads pipelined 2 deep (idx) / 1 deep (table row).
// ---------------------------------------------------------------------------
__global__ __launch_bounds__(256) void lstm_tbl_kernel(
    const int*   __restrict__ x,
    const float* __restrict__ tbl,
    const float* __restrict__ Whh,
    const float* __restrict__ Wfc,
    const float* __restrict__ bfc,
    float*       __restrict__ out)
{
    __shared__ int   idx_lds[T_LEN][16];   // [t][local_batch] 32 KB
    __shared__ float hx[4 * 64];           // per-wave h-exchange, 1 KB

    const int tid  = threadIdx.x;
    const int wv   = tid >> 6;            // wave in block
    const int lane = tid & 63;
    const int j    = lane & 15;           // hidden unit owned
    const int g    = lane >> 4;           // group (batch) within wave
    const int lb   = tid >> 4;            // local batch 0..15
    const int batch = blockIdx.x * 16 + lb;

    for (int i = tid; i < 16 * T_LEN; i += 256) {
        int b = i >> 9;
        int t = i & (T_LEN - 1);
        idx_lds[t][b] = x[(blockIdx.x * 16 + b) * T_LEN + t];
    }

    // per-lane recurrent weights as float2 pairs (v_pk_fma_f32 target)
    v2f w[4][8];
    #pragma unroll
    for (int q = 0; q < 4; ++q) {
        const int r = j + 16 * q;
        #pragma unroll
        for (int p = 0; p < 8; ++p)
            w[q][p] = (v2f){Whh[r * NHID + 2 * p], Whh[r * NHID + 2 * p + 1]};
    }

    __syncthreads();

    v2f h2[8];
    #pragma unroll
    for (int p = 0; p < 8; ++p) h2[p] = (v2f){0.f, 0.f};
    float c = 0.f;

    const float NL2E  = -1.44269504088896f;
    const float NL2E2 = -2.88539008177793f;
    const int hxW = wv * 64;                 // wave-private exchange base
    const float4* hp = (const float4*)&hx[hxW + g * 16];

    // pipeline: tb = xproj row for t, idx_n = token for t+1, idx_nn = t+2
    float4 tb = ((const float4*)tbl)[(long)idx_lds[0][lb] * 16 + j];
    int idx_n  = idx_lds[1][lb];

    #pragma unroll 2
    for (int t = 0; t < T_LEN; ++t) {
        float4 tbn;
        if (t + 1 < T_LEN)
            tbn = ((const float4*)tbl)[(long)idx_n * 16 + j];
        const int idx_nn = (t + 2 < T_LEN) ? idx_lds[t + 2][lb] : 0;

        // gate pre-activations: acc starts at xproj (bias folded in table)
        v2f a0 = (v2f){tb.x, 0.f}, a1 = (v2f){tb.y, 0.f};
        v2f a2 = (v2f){tb.z, 0.f}, a3 = (v2f){tb.w, 0.f};
        #pragma unroll
        for (int p = 0; p < 8; ++p) {
            a0 += h2[p] * w[0][p];
            a1 += h2[p] * w[1][p];
            a2 += h2[p] * w[2][p];
            a3 += h2[p] * w[3][p];
        }
        const float vi = a0.x + a0.y, vf = a1.x + a1.y;
        const float vg = a2.x + a2.y, vo = a3.x + a3.y;

        const float ig = __builtin_amdgcn_rcpf(1.f + __builtin_amdgcn_exp2f(vi * NL2E));
        const float fg = __builtin_amdgcn_rcpf(1.f + __builtin_amdgcn_exp2f(vf * NL2E));
        const float gg = 2.f * __builtin_amdgcn_rcpf(1.f + __builtin_amdgcn_exp2f(vg * NL2E2)) - 1.f;
        const float og = __builtin_amdgcn_rcpf(1.f + __builtin_amdgcn_exp2f(vo * NL2E));

        c = fg * c + ig * gg;
        const float tc = 2.f * __builtin_amdgcn_rcpf(1.f + __builtin_amdgcn_exp2f(c * NL2E2)) - 1.f;
        const float hv = og * tc;

        // h-exchange: each lane writes its hv, group reads back 16 floats
        hx[hxW + lane] = hv;
        const float4 b0 = hp[0], b1 = hp[1], b2 = hp[2], b3 = hp[3];
        h2[0] = (v2f){b0.x, b0.y}; h2[1] = (v2f){b0.z, b0.w};
        h2[2] = (v2f){b1.x, b1.y}; h2[3] = (v2f){b1.z, b1.w};
        h2[4] = (v2f){b2.x, b2.y}; h2[5] = (v2f){b2.z, b2.w};
        h2[6] = (v2f){b3.x, b3.y}; h2[7] = (v2f){b3.z, b3.w};

        tb = tbn; idx_n = idx_nn;
    }

    if (j == 0) {
        float logit = bfc[0];
        #pragma unroll
        for (int p = 0; p < 8; ++p)
            logit += h2[p].x * Wfc[2 * p] + h2[p].y * Wfc[2 * p + 1];
        out[batch] = __builtin_amdgcn_rcpf(1.f + __builtin_amdgcn_exp2f(logit * NL2E));
    }
}

// ---------------------------------------------------------------------------
// Fallback (ws too small): on-the-fly xproj from emb + Wih registers, with
// the same h-exchange scheme. Same structure as the R1 kernel otherwise.
// ---------------------------------------------------------------------------
__global__ __launch_bounds__(256) void lstm_fb_kernel(
    const int*   __restrict__ x,
    const float* __restrict__ emb,
    const float* __restrict__ Wih,
    const float* __restrict__ Whh,
    const float* __restrict__ bih,
    const float* __restrict__ bhh,
    const float* __restrict__ Wfc,
    const float* __restrict__ bfc,
    float*       __restrict__ out)
{
    __shared__ int   idx_lds[T_LEN][16];
    __shared__ float hx[4 * 64];

    const int tid  = threadIdx.x;
    const int wv   = tid >> 6;
    const int lane = tid & 63;
    const int j    = lane & 15;
    const int g    = lane >> 4;
    const int lb   = tid >> 4;
    const int batch = blockIdx.x * 16 + lb;

    for (int i = tid; i < 16 * T_LEN; i += 256) {
        int b = i >> 9;
        int t = i & (T_LEN - 1);
        idx_lds[t][b] = x[(blockIdx.x * 16 + b) * T_LEN + t];
    }

    float wih[4][NEMB], bias[4];
    v2f w[4][8];
    #pragma unroll
    for (int q = 0; q < 4; ++q) {
        const int r = j + 16 * q;
        #pragma unroll
        for (int e = 0; e < NEMB; ++e) wih[q][e] = Wih[r * NEMB + e];
        #pragma unroll
        for (int p = 0; p < 8; ++p)
            w[q][p] = (v2f){Whh[r * NHID + 2 * p], Whh[r * NHID + 2 * p + 1]};
        bias[q] = bih[r] + bhh[r];
    }

    __syncthreads();

    v2f h2[8];
    #pragma unroll
    for (int p = 0; p < 8; ++p) h2[p] = (v2f){0.f, 0.f};
    float c = 0.f;

    const float NL2E  = -1.44269504088896f;
    const float NL2E2 = -2.88539008177793f;
    const int hxW = wv * 64;
    const float4* hp = (const float4*)&hx[hxW + g * 16];

    float2 xa, xb, xc, xd, xe2;
    {
        const float2* er = (const float2*)(emb + (long)idx_lds[0][lb] * NEMB);
        xa = er[0]; xb = er[1]; xc = er[2]; xd = er[3]; xe2 = er[4];
    }
    int idx_n = idx_lds[1][lb];

    #pragma unroll 1
    for (int t = 0; t < T_LEN; ++t) {
        const float xv[NEMB] = {xa.x, xa.y, xb.x, xb.y, xc.x, xc.y,
                                xd.x, xd.y, xe2.x, xe2.y};
        if (t + 1 < T_LEN) {
            const float2* er = (const float2*)(emb + (long)idx_n * NEMB);
            xa = er[0]; xb = er[1]; xc = er[2]; xd = er[3]; xe2 = er[4];
        }
        const int idx_nn = (t + 2 < T_LEN) ? idx_lds[t + 2][lb] : 0;

        float v[4];
        #pragma unroll
        for (int q = 0; q < 4; ++q) {
            float a = bias[q];
            #pragma unroll
            for (int e = 0; e < NEMB; ++e) a += xv[e] * wih[q][e];
            v[q] = a;
        }
        v2f a0 = (v2f){v[0], 0.f}, a1 = (v2f){v[1], 0.f};
        v2f a2 = (v2f){v[2], 0.f}, a3 = (v2f){v[3], 0.f};
        #pragma unroll
        for (int p = 0; p < 8; ++p) {
            a0 += h2[p] * w[0][p];
            a1 += h2[p] * w[1][p];
            a2 += h2[p] * w[2][p];
            a3 += h2[p] * w[3][p];
        }
        const float vi = a0.x + a0.y, vf = a1.x + a1.y;
        const float vg = a2.x + a2.y, vo = a3.x + a3.y;

        const float ig = __builtin_amdgcn_rcpf(1.f + __builtin_amdgcn_exp2f(vi * NL2E));
        const float fg = __builtin_amdgcn_rcpf(1.f + __builtin_amdgcn_exp2f(vf * NL2E));
        const float gg = 2.f * __builtin_amdgcn_rcpf(1.f + __builtin_amdgcn_exp2f(vg * NL2E2)) - 1.f;
        const float og = __builtin_amdgcn_rcpf(1.f + __builtin_amdgcn_exp2f(vo * NL2E));

        c = fg * c + ig * gg;
        const float tc = 2.f * __builtin_amdgcn_rcpf(1.f + __builtin_amdgcn_exp2f(c * NL2E2)) - 1.f;
        const float hv = og * tc;

        hx[hxW + lane] = hv;
        const float4 b0 = hp[0], b1 = hp[1], b2 = hp[2], b3 = hp[3];
        h2[0] = (v2f){b0.x, b0.y}; h2[1] = (v2f){b0.z, b0.w};
        h2[2] = (v2f){b1.x, b1.y}; h2[3] = (v2f){b1.z, b1.w};
        h2[4] = (v2f){b2.x, b2.y}; h2[5] = (v2f){b2.z, b2.w};
        h2[6] = (v2f){b3.x, b3.y}; h2[7] = (v2f){b3.z, b3.w};

        idx_n = idx_nn;
    }

    if (j == 0) {
        float logit = bfc[0];
        #pragma unroll
        for (int p = 0; p < 8; ++p)
            logit += h2[p].x * Wfc[2 * p] + h2[p].y * Wfc[2 * p + 1];
        out[batch] = __builtin_amdgcn_rcpf(1.f + __builtin_amdgcn_exp2f(logit * NL2E));
    }
}

extern "C" void kernel_launch(void* const* d_in, const int* in_sizes, int n_in,
                              void* d_out, int out_size, void* d_ws, size_t ws_size,
                              hipStream_t stream) {
    const int*   x   = (const int*)  d_in[0];
    const float* emb = (const float*)d_in[1];
    const float* Wih = (const float*)d_in[2];
    const float* Whh = (const float*)d_in[3];
    const float* bih = (const float*)d_in[4];
    const float* bhh = (const float*)d_in[5];
    const float* Wfc = (const float*)d_in[6];
    const float* bfc = (const float*)d_in[7];
    float* outp = (float*)d_out;

    const int B = in_sizes[0] / T_LEN;                    // 4096
    const size_t TABLE_BYTES = (size_t)VOCAB1 * 64 * sizeof(float);  // 12.8 MB

    if (ws_size >= TABLE_BYTES) {
        float* tbl = (float*)d_ws;
        build_table<<<(VOCAB1 * 16 + 255) / 256, 256, 0, stream>>>(emb, Wih, bih, bhh, tbl);
        lstm_tbl_kernel<<<B / 16, 256, 0, stream>>>(x, tbl, Whh, Wfc, bfc, outp);
    } else {
        lstm_fb_kernel<<<B / 16, 256, 0, stream>>>(x, emb, Wih, Whh, bih, bhh, Wfc, bfc, outp);
    }
}